// Round 2
// baseline (2862.163 us; speedup 1.0000x reference)
//
#include <hip/hip_runtime.h>
#include <stdint.h>

#define NN 2048
#define DD 512
#define NWORDS 8

typedef unsigned int u32;
typedef unsigned char u8;

__device__ __forceinline__ float sigmoidf_(float x){ return 1.0f/(1.0f+expf(-x)); }

// ---------------- build adjacency bitmask ----------------
__global__ void k_zero_bm(u32* bm){ int t = blockIdx.x*256+threadIdx.x; if(t<NN*NWORDS) bm[t]=0u; }

__global__ void k_scatter(const int* __restrict__ ei, u32* __restrict__ bm){
  int t = blockIdx.x*256+threadIdx.x;
  if(t>=32768) return;
  int r = ei[t];
  int c = ei[32768+t];
  atomicOr(&bm[r*NWORDS + ((c>>5)&7)], 1u<<(c&31));
}

// bm2[r] = OR over neighbors k of bm[k]; deg[r]=popcount(row)
__global__ void k_bm2_deg(const u32* __restrict__ bm, u32* __restrict__ bm2, int* __restrict__ deg){
  int r = blockIdx.x*256+threadIdx.x;
  if(r>=NN) return;
  int base = r & ~255;
  u32 acc[NWORDS];
  #pragma unroll
  for(int w=0;w<NWORDS;++w) acc[w]=0u;
  int d=0;
  #pragma unroll
  for(int w=0;w<NWORDS;++w){
    u32 m = bm[r*NWORDS+w];
    d += __popc(m);
    int b0 = w<<5;
    while(m){ int j=__ffs((int)m)-1; m&=m-1;
      const u32* row = bm + (size_t)(base+b0+j)*NWORDS;
      #pragma unroll
      for(int w2=0;w2<NWORDS;++w2) acc[w2] |= row[w2];
    }
  }
  #pragma unroll
  for(int w=0;w<NWORDS;++w) bm2[r*NWORDS+w]=acc[w];
  deg[r]=d;
}

// ---------------- Vn ----------------
__global__ void k_vn(const float* __restrict__ x, const u32* __restrict__ bm,
                     const int* __restrict__ deg, float* __restrict__ Vn){
  int node = blockIdx.x*4 + (threadIdx.x>>6);
  int lane = threadIdx.x & 63;
  int base = node & ~255;
  float degf = (float)deg[node];
  float ax[8], axx[8];
  #pragma unroll
  for(int k=0;k<8;++k){ ax[k]=0.0f; axx[k]=0.0f; }
  #pragma unroll
  for(int w=0;w<NWORDS;++w){
    u32 m = bm[node*NWORDS+w]; int b0=w<<5;
    while(m){ int j=__ffs((int)m)-1; m&=m-1;
      const float* xr = x + (size_t)(base+b0+j)*DD;
      #pragma unroll
      for(int k=0;k<8;++k){ float v = xr[lane+64*k]; ax[k]+=v; axx[k]=fmaf(v,v,axx[k]); }
    }
  }
  const float* xi = x + (size_t)node*DD;
  double vn2 = 0.0;
  #pragma unroll
  for(int k=0;k<8;++k){
    float xf = xi[lane+64*k];
    float val = xf*(degf*xf - ax[k]) - xf*ax[k] + axx[k];
    vn2 += (double)val*(double)val;
  }
  #pragma unroll
  for(int off=32;off>0;off>>=1) vn2 += __shfl_down(vn2, off);
  if(lane==0) Vn[node] = (float)sqrt(vn2);
}

// ---------------- per-graph softmax entropy ----------------
__global__ void k_softent(const float* __restrict__ Vn, float* __restrict__ ent){
  __shared__ float red[4];
  __shared__ float sh;
  int g = blockIdx.x, tid = threadIdx.x;
  float v = Vn[g*256+tid];
  float m = v;
  #pragma unroll
  for(int off=32;off>0;off>>=1) m = fmaxf(m, __shfl_down(m,off));
  if((tid&63)==0) red[tid>>6]=m;
  __syncthreads();
  if(tid==0) sh = fmaxf(fmaxf(red[0],red[1]),fmaxf(red[2],red[3]));
  __syncthreads();
  float mx = sh;
  float e = expf(v-mx);
  float s = e;
  #pragma unroll
  for(int off=32;off>0;off>>=1) s += __shfl_down(s,off);
  if((tid&63)==0) red[tid>>6]=s;
  __syncthreads();
  if(tid==0) sh = red[0]+red[1]+red[2]+red[3];
  __syncthreads();
  float Pn = e / sh;
  if(Pn==0.0f) Pn=1.0f;
  ent[g*256+tid] = -Pn*logf(Pn);
}

// u = ent + A@ent
__global__ void k_u(const u32* __restrict__ bm, const float* __restrict__ ent, float* __restrict__ uo){
  int i = blockIdx.x*256+threadIdx.x;
  if(i>=NN) return;
  int base = i & ~255;
  float acc = ent[i];
  #pragma unroll
  for(int w=0;w<NWORDS;++w){
    u32 m = bm[i*NWORDS+w]; int b0=w<<5;
    while(m){ int j=__ffs((int)m)-1; m&=m-1; acc += ent[base+b0+j]; }
  }
  uo[i]=acc;
}

// h1 = relu(u * w11 + b11)
__global__ void k_h1(const float* __restrict__ u, const float* __restrict__ w11,
                     const float* __restrict__ b11, float* __restrict__ h){
  int t = blockIdx.x*256+threadIdx.x;
  if(t>=NN*DD) return;
  int i = t>>9; int f = t&511;
  h[t] = fmaxf(fmaf(u[i], w11[f], b11[f]), 0.0f);
}

// ---------------- tiled fp32 GEMM ----------------
template<int ACT>
__global__ __launch_bounds__(256) void k_gemm(const float* __restrict__ A, const float* __restrict__ B,
                                              const float* __restrict__ bias, float* __restrict__ C){
  __shared__ float As[32][68];
  __shared__ float Bs[32][68];
  int tid = threadIdx.x;
  int m0 = blockIdx.x*64;
  int n0 = blockIdx.y*64;
  int ty = tid>>4, tx = tid&15;
  float acc[4][4];
  #pragma unroll
  for(int i=0;i<4;++i){
    #pragma unroll
    for(int j=0;j<4;++j) acc[i][j]=0.0f;
  }
  for(int k0=0;k0<512;k0+=32){
    __syncthreads();
    #pragma unroll
    for(int t0=0;t0<2;++t0){
      int t = tid + t0*256;
      int row = t>>3, c4 = t&7;
      float4 v = *(const float4*)(A + (size_t)(m0+row)*512 + k0 + c4*4);
      As[c4*4+0][row]=v.x; As[c4*4+1][row]=v.y; As[c4*4+2][row]=v.z; As[c4*4+3][row]=v.w;
    }
    #pragma unroll
    for(int t0=0;t0<2;++t0){
      int t = tid + t0*256;
      int row = t>>4, c4 = t&15;
      float4 v = *(const float4*)(B + (size_t)(k0+row)*512 + n0 + c4*4);
      *(float4*)&Bs[row][c4*4] = v;
    }
    __syncthreads();
    #pragma unroll
    for(int kk=0;kk<32;++kk){
      float4 a = *(const float4*)&As[kk][ty*4];
      float4 b = *(const float4*)&Bs[kk][tx*4];
      float av[4]={a.x,a.y,a.z,a.w}, bv[4]={b.x,b.y,b.z,b.w};
      #pragma unroll
      for(int i=0;i<4;++i){
        #pragma unroll
        for(int j=0;j<4;++j) acc[i][j] = fmaf(av[i],bv[j],acc[i][j]);
      }
    }
  }
  #pragma unroll
  for(int i=0;i<4;++i){
    float4 o;
    float* oo = &o.x;
    #pragma unroll
    for(int j=0;j<4;++j){
      float v = acc[i][j] + bias[n0+tx*4+j];
      if(ACT==0) v = fmaxf(v,0.0f);
      else      v = 1.0f/(1.0f+expf(-v));
      oo[j]=v;
    }
    *(float4*)(C + (size_t)(m0+ty*4+i)*512 + n0 + tx*4) = o;
  }
}

// out = h + A@h
__global__ void k_spmm_add(const float* __restrict__ h, const u32* __restrict__ bm, float* __restrict__ out){
  int node = blockIdx.x*4 + (threadIdx.x>>6);
  int lane = threadIdx.x & 63;
  int base = node & ~255;
  float acc[8];
  #pragma unroll
  for(int k=0;k<8;++k) acc[k] = h[(size_t)node*DD + lane + 64*k];
  #pragma unroll
  for(int w=0;w<NWORDS;++w){
    u32 m = bm[node*NWORDS+w]; int b0=w<<5;
    while(m){ int j=__ffs((int)m)-1; m&=m-1;
      const float* hr = h + (size_t)(base+b0+j)*DD;
      #pragma unroll
      for(int k=0;k<8;++k) acc[k] += hr[lane+64*k];
    }
  }
  #pragma unroll
  for(int k=0;k<8;++k) out[(size_t)node*DD + lane + 64*k] = acc[k];
}

// prob = sigmoid(sigmoid(h@w33 + b33))
__global__ void k_gemv_prob(const float* __restrict__ h, const float* __restrict__ w33,
                            const float* __restrict__ b33, float* __restrict__ prob){
  int node = blockIdx.x*4 + (threadIdx.x>>6);
  int lane = threadIdx.x & 63;
  float acc = 0.0f;
  #pragma unroll
  for(int k=0;k<8;++k) acc = fmaf(h[(size_t)node*512 + lane + 64*k], w33[lane+64*k], acc);
  #pragma unroll
  for(int off=32;off>0;off>>=1) acc += __shfl_down(acc, off);
  if(lane==0){
    float z = sigmoidf_(acc + b33[0]);
    prob[node] = sigmoidf_(z);
  }
}

// ---------------- y = A@prob (fp64), per-graph c_g and gamma partials ----------------
__global__ __launch_bounds__(256) void k_y(const u32* __restrict__ bm, const float* __restrict__ prob,
                 const float* __restrict__ ent, double* __restrict__ y,
                 double* __restrict__ cg, double* __restrict__ gam){
  __shared__ float p_s[256];
  __shared__ double redc[4], redg[4];
  int g = blockIdx.x, i = threadIdx.x;
  int node = (g<<8) + i;
  float p = prob[node];
  p_s[i] = p;
  __syncthreads();
  double acc = 0.0;
  #pragma unroll
  for (int w = 0; w < NWORDS; ++w){
    u32 m = bm[(size_t)node*NWORDS + w];
    while (m){ int j=__ffs((int)m)-1; m&=m-1; acc += (double)p_s[(w<<5)+j]; }
  }
  y[node] = acc;
  double e = (double)ent[node];
  double c = (double)p*acc - e*(double)p;
  #pragma unroll
  for (int off=32; off>0; off>>=1){ c += __shfl_down(c,off); e += __shfl_down(e,off); }
  if ((i&63)==0){ redc[i>>6]=c; redg[i>>6]=e; }
  __syncthreads();
  if (i==0){ cg[g]=redc[0]+redc[1]+redc[2]+redc[3]; gam[g]=redg[0]+redg[1]+redg[2]+redg[3]; }
}

// ---------------- bitonic sort: order = argsort(-prob) stable ----------------
__global__ void k_sort(const float* __restrict__ prob, int* __restrict__ order){
  __shared__ float kp[NN];
  __shared__ int ki[NN];
  int tid = threadIdx.x; // 1024
  for(int t=tid;t<NN;t+=1024){ kp[t]=prob[t]; ki[t]=t; }
  __syncthreads();
  for(int k=2;k<=NN;k<<=1){
    for(int j=k>>1;j>0;j>>=1){
      for(int t=tid;t<NN;t+=1024){
        int l = t ^ j;
        if(l > t){
          bool up = ((t & k) == 0);
          float pa=kp[t]; int ia=ki[t]; float pb=kp[l]; int ib=ki[l];
          bool before_ab = (pa > pb) || (pa == pb && ia < ib);
          bool dosw = up ? (!before_ab) : before_ab;
          if(dosw){ kp[t]=pb; ki[t]=ib; kp[l]=pa; ki[l]=ia; }
        }
      }
      __syncthreads();
    }
  }
  for(int t=tid;t<NN;t+=1024) order[t]=ki[t];
}

// ---------------- single-wave incremental greedy scan ----------------
// Lane l owns: columns [4l..4l+4) of the active graph; nodes [32l..32l+32) for
// dead/sel bitmasks (held in registers, queried via __shfl).
// Maintains: dummy (f32 LDS), y=A@dummy (f64 LDS), scalar totC (f64, replicated).
// Delta = sum_{c in S} u_c*(2y_c - e_c) + 2*u_v*sum_nb(u_j) + sum_{i,j in nb} d_i A_ij d_j
__global__ void __launch_bounds__(64) k_scan(const u32* __restrict__ bm, const int* __restrict__ deg,
    const float* __restrict__ ent, const float* __restrict__ prob, const int* __restrict__ order,
    const double* __restrict__ yg, const double* __restrict__ cgp, const double* __restrict__ gamp,
    float* __restrict__ selw, float* __restrict__ out_sel, float* __restrict__ out_loss)
{
  extern __shared__ char smem[];
  u32* bm_s      = (u32*)smem;                    // 64 KB
  float* dummy_s = (float*)(bm_s + NN*NWORDS);    // 8 KB
  float* entf_s  = dummy_s + NN;                  // 8 KB
  double* y_s    = (double*)(entf_s + NN);        // 16 KB (8-aligned: offset 80 KB)
  int* order_s   = (int*)(y_s + NN);              // 8 KB
  float* u_scr   = (float*)(order_s + NN);        // 1 KB (active-graph scratch)
  int lane = threadIdx.x;

  for (int t = lane; t < NN*NWORDS; t += 64) bm_s[t] = bm[t];
  for (int t = lane; t < NN; t += 64){
    dummy_s[t] = prob[t];
    entf_s[t]  = ent[t];
    y_s[t]     = yg[t];
    order_s[t] = order[t];
  }
  u32 myDead = 0, mySel = 0;
  #pragma unroll 4
  for (int k = 0; k < 32; ++k){
    int node = lane*32 + k;
    if (deg[node] == 0){ myDead |= 1u<<k; mySel |= 1u<<k; }
  }
  double totC = 0.0, gamma = 0.0;
  #pragma unroll
  for (int g = 0; g < 8; ++g){ totC += cgp[g]; gamma += gamp[g]; }
  const double loss = gamma + totC;
  if (lane == 0) out_loss[0] = (float)loss;
  __syncthreads();

  int nxt = order_s[0];
  for (int t = 0; t < NN; ++t){
    int node = nxt;
    if (t+1 < NN) nxt = order_s[t+1];
    u32 dw = __shfl(myDead, node>>5);
    if ((dw >> (node&31)) & 1u) continue;

    // ---- eligible evaluation ----
    int g = node >> 8, base = node & ~255, r = node & 255;
    u32 rv[8];
    #pragma unroll
    for (int w = 0; w < 8; ++w) rv[w] = bm_s[node*NWORDS + w];
    float dv = dummy_s[node];
    float uv = 1.0f - dv;

    double dsum = 0.0, accU = 0.0;
    float uc_[4];
    #pragma unroll
    for (int q = 0; q < 4; ++q){
      int c = lane*4 + q;
      int isnb = (rv[c>>5] >> (c&31)) & 1;
      float d = dummy_s[base + c];
      float uc = 0.0f;
      if (c == r) uc = uv;
      else if (isnb) uc = -d;
      uc_[q] = uc;
      if (uc != 0.0f)
        dsum += (double)uc * (2.0*y_s[base+c] - (double)entf_s[base+c]);
      if (isnb){
        accU -= (double)d;
        double ps = 0.0;
        #pragma unroll
        for (int w = 0; w < 8; ++w){
          u32 m = bm_s[(size_t)(base+c)*NWORDS + w] & rv[w];
          while (m){ int j=__ffs((int)m)-1; m&=m-1; ps += (double)dummy_s[base + (w<<5) + j]; }
        }
        dsum += (double)d * ps;
      }
    }
    #pragma unroll
    for (int off = 1; off < 64; off <<= 1){
      dsum += __shfl_xor(dsum, off);
      accU += __shfl_xor(accU, off);
    }
    double delta = dsum + 2.0 * (double)uv * accU;

    if (gamma + totC + delta <= loss){
      // ---- take ----
      totC += delta;
      #pragma unroll
      for (int q = 0; q < 4; ++q){
        int c = lane*4 + q;
        u_scr[c] = uc_[q];
        if (uc_[q] != 0.0f) dummy_s[base+c] = (c==r) ? 1.0f : 0.0f;
      }
      if (lane == (node>>5)) mySel |= 1u << (node&31);
      {
        int w = lane - g*8;
        if (w >= 0 && w < 8){
          u32 sm = rv[w];
          if (w == (r>>5)) sm |= 1u << (r&31);
          myDead |= sm;
        }
      }
      __syncthreads(); // u_scr visible wave-wide
      u32 suppm[8];
      #pragma unroll
      for (int w = 0; w < 8; ++w) suppm[w] = rv[w];
      suppm[r>>5] |= 1u << (r&31);
      #pragma unroll
      for (int q = 0; q < 4; ++q){
        int c = lane*4 + q;
        double dy = 0.0;
        #pragma unroll
        for (int w = 0; w < 8; ++w){
          u32 m = bm_s[(size_t)(base+c)*NWORDS + w] & suppm[w];
          while (m){ int j=__ffs((int)m)-1; m&=m-1; dy += (double)u_scr[(w<<5)+j]; }
        }
        if (dy != 0.0) y_s[base+c] += dy;
      }
      __syncthreads(); // dummy/y visible before next eval
    }
  }

  #pragma unroll 4
  for (int k = 0; k < 32; ++k){
    int node = lane*32 + k;
    float sv = ((mySel >> k) & 1u) ? 1.0f : 0.0f;
    selw[node] = sv; out_sel[node] = sv;
  }
}

// ---------------- outputs ----------------
__global__ void k_xpool(const float* __restrict__ x, const float* __restrict__ selw, float* __restrict__ out){
  int t = blockIdx.x*256+threadIdx.x;
  if(t >= NN*(DD/4)) return;
  int i = t >> 7;
  float s = selw[i];
  float4 v = ((const float4*)x)[t];
  v.x*=s; v.y*=s; v.z*=s; v.w*=s;
  ((float4*)out)[t] = v;
}

__global__ void k_adj(const u32* __restrict__ bm, const u32* __restrict__ bm2,
                      const float* __restrict__ selw, float* __restrict__ outadj){
  int r = blockIdx.x;
  int c = blockIdx.y*256 + threadIdx.x;
  float val = 0.0f;
  if ((r>>8)==(c>>8) && r!=c && selw[r]!=0.0f && selw[c]!=0.0f){
    int lc = c & 255;
    u32 any = (bm2[r*NWORDS + (lc>>5)] >> (lc&31)) & 1u;
    if(!any){
      #pragma unroll
      for(int w=0;w<NWORDS;++w) any |= (bm2[r*NWORDS+w] & bm[c*NWORDS+w]);
    }
    val = any ? 1.0f : 0.0f;
  }
  outadj[(size_t)r*2048 + c] = val;
}

extern "C" void kernel_launch(void* const* d_in, const int* in_sizes, int n_in,
                              void* d_out, int out_size, void* d_ws, size_t ws_size,
                              hipStream_t stream){
  const float* x  = (const float*)d_in[0];
  const int* ei   = (const int*)d_in[1];
  const float* w11=(const float*)d_in[3];  const float* b11=(const float*)d_in[4];
  const float* w12=(const float*)d_in[5];  const float* b12=(const float*)d_in[6];
  const float* w13=(const float*)d_in[7];  const float* b13=(const float*)d_in[8];
  const float* w21=(const float*)d_in[9];  const float* b21=(const float*)d_in[10];
  const float* w22=(const float*)d_in[11]; const float* b22=(const float*)d_in[12];
  const float* w23=(const float*)d_in[13]; const float* b23=(const float*)d_in[14];
  const float* w31=(const float*)d_in[15]; const float* b31=(const float*)d_in[16];
  const float* w32=(const float*)d_in[17]; const float* b32=(const float*)d_in[18];
  const float* w33=(const float*)d_in[19]; const float* b33=(const float*)d_in[20];

  char* ws = (char*)d_ws;
  u32* bm    = (u32*)(ws + 0);
  u32* bm2   = (u32*)(ws + 65536);
  int* deg   = (int*)(ws + 131072);
  float* Vn  = (float*)(ws + 139264);
  float* ent = (float*)(ws + 147456);
  float* uarr= (float*)(ws + 155648);
  float* prob= (float*)(ws + 163840);
  int* order = (int*)(ws + 172032);
  float* selw= (float*)(ws + 180224);
  double* yg = (double*)(ws + 196608);
  double* cg = (double*)(ws + 212992);
  double* gam= (double*)(ws + 213056);
  float* buf0= (float*)(ws + (1<<20));
  float* buf1= (float*)(ws + (1<<20) + (size_t)NN*DD*4);

  float* out = (float*)d_out;
  float* out_xp   = out;
  float* out_adj  = out + 1048576;
  float* out_sel  = out + 1048576 + 4194304;
  float* out_loss = out + 1048576 + 4194304 + 2048;

  hipFuncSetAttribute((const void*)k_scan, hipFuncAttributeMaxDynamicSharedMemorySize, 107520);

  k_zero_bm<<<64,256,0,stream>>>(bm);
  k_scatter<<<128,256,0,stream>>>(ei, bm);
  k_bm2_deg<<<8,256,0,stream>>>(bm, bm2, deg);
  k_vn<<<512,256,0,stream>>>(x, bm, deg, Vn);
  k_softent<<<8,256,0,stream>>>(Vn, ent);
  k_u<<<8,256,0,stream>>>(bm, ent, uarr);
  k_h1<<<4096,256,0,stream>>>(uarr, w11, b11, buf0);
  dim3 gg(32,8);
  k_gemm<0><<<gg,256,0,stream>>>(buf0, w12, b12, buf1);
  k_gemm<1><<<gg,256,0,stream>>>(buf1, w13, b13, buf0);
  k_spmm_add<<<512,256,0,stream>>>(buf0, bm, buf1);
  k_gemm<0><<<gg,256,0,stream>>>(buf1, w21, b21, buf0);
  k_gemm<0><<<gg,256,0,stream>>>(buf0, w22, b22, buf1);
  k_gemm<1><<<gg,256,0,stream>>>(buf1, w23, b23, buf0);
  k_spmm_add<<<512,256,0,stream>>>(buf0, bm, buf1);
  k_gemm<0><<<gg,256,0,stream>>>(buf1, w31, b31, buf0);
  k_gemm<0><<<gg,256,0,stream>>>(buf0, w32, b32, buf1);
  k_gemv_prob<<<512,256,0,stream>>>(buf1, w33, b33, prob);
  k_y<<<8,256,0,stream>>>(bm, prob, ent, yg, cg, gam);
  k_sort<<<1,1024,0,stream>>>(prob, order);
  k_scan<<<1,64,107520,stream>>>(bm, deg, ent, prob, order, yg, cg, gam, selw, out_sel, out_loss);
  k_xpool<<<1024,256,0,stream>>>(x, selw, out_xp);
  dim3 ga(2048,8);
  k_adj<<<ga,256,0,stream>>>(bm, bm2, selw, out_adj);
}

// Round 5
// 2543.682 us; speedup vs baseline: 1.1252x; 1.1252x over previous
//
#include <hip/hip_runtime.h>
#include <stdint.h>

#define NN 2048
#define DD 512
#define NWORDS 8

typedef unsigned int u32;
typedef unsigned char u8;

__device__ __forceinline__ float sigmoidf_(float x){ return 1.0f/(1.0f+expf(-x)); }

// ---------------- build adjacency bitmask ----------------
__global__ void k_zero_bm(u32* bm, u32* dead0){
  int t = blockIdx.x*256+threadIdx.x;
  if(t<NN*NWORDS) bm[t]=0u;
  else if(t<NN*NWORDS+64) dead0[t-NN*NWORDS]=0u;
}

__global__ void k_scatter(const int* __restrict__ ei, u32* __restrict__ bm){
  int t = blockIdx.x*256+threadIdx.x;
  if(t>=32768) return;
  int r = ei[t];
  int c = ei[32768+t];
  atomicOr(&bm[r*NWORDS + ((c>>5)&7)], 1u<<(c&31));
}

// bm2[r] = OR over neighbors of bm[k]; deg; neighbor lists (u8 local col, padded 48); dead0 bits
__global__ void k_bm2_deg(const u32* __restrict__ bm, u32* __restrict__ bm2, int* __restrict__ deg,
                          u8* __restrict__ nbrl, u8* __restrict__ cntg, u32* __restrict__ dead0){
  int r = blockIdx.x*256+threadIdx.x;
  if(r>=NN) return;
  int base = r & ~255;
  u32 acc[NWORDS];
  #pragma unroll
  for(int w=0;w<NWORDS;++w) acc[w]=0u;
  int idx=0;
  #pragma unroll
  for(int w=0;w<NWORDS;++w){
    u32 m = bm[r*NWORDS+w];
    int b0 = w<<5;
    while(m){ int j=__ffs((int)m)-1; m&=m-1;
      if(idx<48) nbrl[(size_t)r*48+idx]=(u8)(b0+j);
      ++idx;
      const u32* row = bm + (size_t)(base+b0+j)*NWORDS;
      #pragma unroll
      for(int w2=0;w2<NWORDS;++w2) acc[w2] |= row[w2];
    }
  }
  #pragma unroll
  for(int w=0;w<NWORDS;++w) bm2[r*NWORDS+w]=acc[w];
  deg[r]=idx;
  cntg[r]=(u8)(idx<48?idx:48);
  if(idx==0) atomicOr(&dead0[r>>5], 1u<<(r&31));
}

// ---------------- Vn ----------------
__global__ void k_vn(const float* __restrict__ x, const u32* __restrict__ bm,
                     const int* __restrict__ deg, float* __restrict__ Vn){
  int node = blockIdx.x*4 + (threadIdx.x>>6);
  int lane = threadIdx.x & 63;
  int base = node & ~255;
  float degf = (float)deg[node];
  float ax[8], axx[8];
  #pragma unroll
  for(int k=0;k<8;++k){ ax[k]=0.0f; axx[k]=0.0f; }
  #pragma unroll
  for(int w=0;w<NWORDS;++w){
    u32 m = bm[node*NWORDS+w]; int b0=w<<5;
    while(m){ int j=__ffs((int)m)-1; m&=m-1;
      const float* xr = x + (size_t)(base+b0+j)*DD;
      #pragma unroll
      for(int k=0;k<8;++k){ float v = xr[lane+64*k]; ax[k]+=v; axx[k]=fmaf(v,v,axx[k]); }
    }
  }
  const float* xi = x + (size_t)node*DD;
  double vn2 = 0.0;
  #pragma unroll
  for(int k=0;k<8;++k){
    float xf = xi[lane+64*k];
    float val = xf*(degf*xf - ax[k]) - xf*ax[k] + axx[k];
    vn2 += (double)val*(double)val;
  }
  #pragma unroll
  for(int off=32;off>0;off>>=1) vn2 += __shfl_down(vn2, off);
  if(lane==0) Vn[node] = (float)sqrt(vn2);
}

// ---------------- per-graph softmax entropy ----------------
__global__ void k_softent(const float* __restrict__ Vn, float* __restrict__ ent){
  __shared__ float red[4];
  __shared__ float sh;
  int g = blockIdx.x, tid = threadIdx.x;
  float v = Vn[g*256+tid];
  float m = v;
  #pragma unroll
  for(int off=32;off>0;off>>=1) m = fmaxf(m, __shfl_down(m,off));
  if((tid&63)==0) red[tid>>6]=m;
  __syncthreads();
  if(tid==0) sh = fmaxf(fmaxf(red[0],red[1]),fmaxf(red[2],red[3]));
  __syncthreads();
  float mx = sh;
  float e = expf(v-mx);
  float s = e;
  #pragma unroll
  for(int off=32;off>0;off>>=1) s += __shfl_down(s,off);
  if((tid&63)==0) red[tid>>6]=s;
  __syncthreads();
  if(tid==0) sh = red[0]+red[1]+red[2]+red[3];
  __syncthreads();
  float Pn = e / sh;
  if(Pn==0.0f) Pn=1.0f;
  ent[g*256+tid] = -Pn*logf(Pn);
}

// u = ent + A@ent
__global__ void k_u(const u32* __restrict__ bm, const float* __restrict__ ent, float* __restrict__ uo){
  int i = blockIdx.x*256+threadIdx.x;
  if(i>=NN) return;
  int base = i & ~255;
  float acc = ent[i];
  #pragma unroll
  for(int w=0;w<NWORDS;++w){
    u32 m = bm[i*NWORDS+w]; int b0=w<<5;
    while(m){ int j=__ffs((int)m)-1; m&=m-1; acc += ent[base+b0+j]; }
  }
  uo[i]=acc;
}

// h1 = relu(u * w11 + b11)
__global__ void k_h1(const float* __restrict__ u, const float* __restrict__ w11,
                     const float* __restrict__ b11, float* __restrict__ h){
  int t = blockIdx.x*256+threadIdx.x;
  if(t>=NN*DD) return;
  int i = t>>9; int f = t&511;
  h[t] = fmaxf(fmaf(u[i], w11[f], b11[f]), 0.0f);
}

// ---------------- tiled fp32 GEMM ----------------
template<int ACT>
__global__ __launch_bounds__(256) void k_gemm(const float* __restrict__ A, const float* __restrict__ B,
                                              const float* __restrict__ bias, float* __restrict__ C){
  __shared__ float As[32][68];
  __shared__ float Bs[32][68];
  int tid = threadIdx.x;
  int m0 = blockIdx.x*64;
  int n0 = blockIdx.y*64;
  int ty = tid>>4, tx = tid&15;
  float acc[4][4];
  #pragma unroll
  for(int i=0;i<4;++i){
    #pragma unroll
    for(int j=0;j<4;++j) acc[i][j]=0.0f;
  }
  for(int k0=0;k0<512;k0+=32){
    __syncthreads();
    #pragma unroll
    for(int t0=0;t0<2;++t0){
      int t = tid + t0*256;
      int row = t>>3, c4 = t&7;
      float4 v = *(const float4*)(A + (size_t)(m0+row)*512 + k0 + c4*4);
      As[c4*4+0][row]=v.x; As[c4*4+1][row]=v.y; As[c4*4+2][row]=v.z; As[c4*4+3][row]=v.w;
    }
    #pragma unroll
    for(int t0=0;t0<2;++t0){
      int t = tid + t0*256;
      int row = t>>4, c4 = t&15;
      float4 v = *(const float4*)(B + (size_t)(k0+row)*512 + n0 + c4*4);
      *(float4*)&Bs[row][c4*4] = v;
    }
    __syncthreads();
    #pragma unroll
    for(int kk=0;kk<32;++kk){
      float4 a = *(const float4*)&As[kk][ty*4];
      float4 b = *(const float4*)&Bs[kk][tx*4];
      float av[4]={a.x,a.y,a.z,a.w}, bv[4]={b.x,b.y,b.z,b.w};
      #pragma unroll
      for(int i=0;i<4;++i){
        #pragma unroll
        for(int j=0;j<4;++j) acc[i][j] = fmaf(av[i],bv[j],acc[i][j]);
      }
    }
  }
  #pragma unroll
  for(int i=0;i<4;++i){
    float4 o;
    float* oo = &o.x;
    #pragma unroll
    for(int j=0;j<4;++j){
      float v = acc[i][j] + bias[n0+tx*4+j];
      if(ACT==0) v = fmaxf(v,0.0f);
      else      v = 1.0f/(1.0f+expf(-v));
      oo[j]=v;
    }
    *(float4*)(C + (size_t)(m0+ty*4+i)*512 + n0 + tx*4) = o;
  }
}

// out = h + A@h
__global__ void k_spmm_add(const float* __restrict__ h, const u32* __restrict__ bm, float* __restrict__ out){
  int node = blockIdx.x*4 + (threadIdx.x>>6);
  int lane = threadIdx.x & 63;
  int base = node & ~255;
  float acc[8];
  #pragma unroll
  for(int k=0;k<8;++k) acc[k] = h[(size_t)node*DD + lane + 64*k];
  #pragma unroll
  for(int w=0;w<NWORDS;++w){
    u32 m = bm[node*NWORDS+w]; int b0=w<<5;
    while(m){ int j=__ffs((int)m)-1; m&=m-1;
      const float* hr = h + (size_t)(base+b0+j)*DD;
      #pragma unroll
      for(int k=0;k<8;++k) acc[k] += hr[lane+64*k];
    }
  }
  #pragma unroll
  for(int k=0;k<8;++k) out[(size_t)node*DD + lane + 64*k] = acc[k];
}

// prob = sigmoid(sigmoid(h@w33 + b33))
__global__ void k_gemv_prob(const float* __restrict__ h, const float* __restrict__ w33,
                            const float* __restrict__ b33, float* __restrict__ prob){
  int node = blockIdx.x*4 + (threadIdx.x>>6);
  int lane = threadIdx.x & 63;
  float acc = 0.0f;
  #pragma unroll
  for(int k=0;k<8;++k) acc = fmaf(h[(size_t)node*512 + lane + 64*k], w33[lane+64*k], acc);
  #pragma unroll
  for(int off=32;off>0;off>>=1) acc += __shfl_down(acc, off);
  if(lane==0){
    float z = sigmoidf_(acc + b33[0]);
    prob[node] = sigmoidf_(z);
  }
}

// ---------------- y = A@prob (fp64), per-graph c_g and gamma partials ----------------
__global__ __launch_bounds__(256) void k_y(const u32* __restrict__ bm, const float* __restrict__ prob,
                 const float* __restrict__ ent, double* __restrict__ y,
                 double* __restrict__ cg, double* __restrict__ gam){
  __shared__ float p_s[256];
  __shared__ double redc[4], redg[4];
  int g = blockIdx.x, i = threadIdx.x;
  int node = (g<<8) + i;
  float p = prob[node];
  p_s[i] = p;
  __syncthreads();
  double acc = 0.0;
  #pragma unroll
  for (int w = 0; w < NWORDS; ++w){
    u32 m = bm[(size_t)node*NWORDS + w];
    while (m){ int j=__ffs((int)m)-1; m&=m-1; acc += (double)p_s[(w<<5)+j]; }
  }
  y[node] = acc;
  double e = (double)ent[node];
  double c = (double)p*acc - e*(double)p;
  #pragma unroll
  for (int off=32; off>0; off>>=1){ c += __shfl_down(c,off); e += __shfl_down(e,off); }
  if ((i&63)==0){ redc[i>>6]=c; redg[i>>6]=e; }
  __syncthreads();
  if (i==0){ cg[g]=redc[0]+redc[1]+redc[2]+redc[3]; gam[g]=redg[0]+redg[1]+redg[2]+redg[3]; }
}

// ---------------- bitonic sort: order = argsort(-prob) stable ----------------
__global__ void k_sort(const float* __restrict__ prob, int* __restrict__ order){
  __shared__ float kp[NN];
  __shared__ int ki[NN];
  int tid = threadIdx.x; // 1024
  for(int t=tid;t<NN;t+=1024){ kp[t]=prob[t]; ki[t]=t; }
  __syncthreads();
  for(int k=2;k<=NN;k<<=1){
    for(int j=k>>1;j>0;j>>=1){
      for(int t=tid;t<NN;t+=1024){
        int l = t ^ j;
        if(l > t){
          bool up = ((t & k) == 0);
          float pa=kp[t]; int ia=ki[t]; float pb=kp[l]; int ib=ki[l];
          bool before_ab = (pa > pb) || (pa == pb && ia < ib);
          bool dosw = up ? (!before_ab) : before_ab;
          if(dosw){ kp[t]=pb; ki[t]=ib; kp[l]=pa; ki[l]=ia; }
        }
      }
      __syncthreads();
    }
  }
  for(int t=tid;t<NN;t+=1024) order[t]=ki[t];
}

// ---------------- single-wave incremental greedy scan, latency-optimized ----------------
// Lane k owns the k-th support node (k=0 self, k>=1 neighbors via precomputed lists).
// All gathers are independent loads; one fused fp64 butterfly; 1-iter-ahead prefetch.
__global__ void __launch_bounds__(64) k_scan(const u32* __restrict__ bm, const u8* __restrict__ nbrl,
    const u8* __restrict__ cntg, const u32* __restrict__ dead0,
    const float* __restrict__ ent, const float* __restrict__ prob, const int* __restrict__ order,
    const double* __restrict__ yg, const double* __restrict__ cgp, const double* __restrict__ gamp,
    float* __restrict__ selw, float* __restrict__ out_sel, float* __restrict__ out_loss)
{
  extern __shared__ char smem[];
  u32* bm_s      = (u32*)smem;                    // 64 KB
  double* y_s    = (double*)(bm_s + NN*NWORDS);   // 16 KB
  float* dummy_s = (float*)(y_s + NN);            // 8 KB
  float* entf_s  = dummy_s + NN;                  // 8 KB
  int* order_s   = (int*)(entf_s + NN);           // 8 KB
  float* mark    = (float*)(order_s + NN);        // 1 KB
  u32* dead_s    = (u32*)(mark + 256);            // 256 B
  u32* sel_s     = dead_s + 64;                   // 256 B
  int lane = threadIdx.x;

  for (int t = lane; t < NN*NWORDS/4; t += 64) ((uint4*)bm_s)[t] = ((const uint4*)bm)[t];
  for (int t = lane; t < NN; t += 64){
    dummy_s[t] = prob[t];
    entf_s[t]  = ent[t];
    y_s[t]     = yg[t];
    order_s[t] = order[t];
  }
  for (int t = lane; t < 256; t += 64) mark[t] = 0.0f;
  { u32 d0 = dead0[lane]; dead_s[lane] = d0; sel_s[lane] = d0; }
  double thr = 0.0;
  if (lane == 0){
    double gg=0.0, cc=0.0;
    for (int i=0;i<8;++i){ gg+=gamp[i]; cc+=cgp[i]; }
    out_loss[0] = (float)(gg+cc);
  }
  __syncthreads();

  int nodeA = order_s[0];
  u32 dwA   = dead_s[nodeA>>5];
  u8 nbA    = nbrl[(size_t)nodeA*48 + (lane==0?0:lane-1)];
  int cntA  = cntg[nodeA];

  for (int t = 0; t < NN; ++t){
    int node = nodeA; u32 dw = dwA; int j0 = nbA; int cnt = cntA;
    int tn = (t+1 < NN) ? t+1 : t;
    nodeA = order_s[tn];
    dwA   = dead_s[nodeA>>5];
    nbA   = nbrl[(size_t)nodeA*48 + (lane==0?0:lane-1)];
    cntA  = cntg[nodeA];
    if ((dw >> (node&31)) & 1u) continue;

    int base = node & ~255, r = node & 255;
    bool act = (lane <= cnt);
    int j = (lane==0) ? r : j0;
    int c = base + j;
    float d  = act ? dummy_s[c] : 0.0f;
    double yv = act ? y_s[c] : 0.0;
    float e  = act ? entf_s[c] : 0.0f;
    u32 rv[8], ri[8];
    #pragma unroll
    for (int w=0; w<8; ++w) rv[w] = bm_s[node*NWORDS + w];
    #pragma unroll
    for (int w=0; w<8; ++w) ri[w] = act ? bm_s[(size_t)c*NWORDS + w] : 0u;
    if (act) mark[j] = d;
    __syncthreads();

    float dv = __shfl(d, 0);
    float uv = 1.0f - dv;
    double part = 0.0;
    if (act){
      float u = (lane==0) ? uv : -d;
      part = (double)u * (2.0*yv - (double)e);
      if (lane > 0){
        double ps = 0.0;
        #pragma unroll
        for (int w=0; w<8; ++w){
          u32 m = ri[w] & rv[w]; int b0 = w<<5;
          while (m){ int jj=__ffs((int)m)-1; m&=m-1; ps += (double)mark[b0+jj]; }
        }
        part += (double)d*ps - 2.0*(double)uv*(double)d;
      }
    }
    #pragma unroll
    for (int off=1; off<64; off<<=1) part += __shfl_xor(part, off);

    if (part <= thr){
      thr -= part;
      if (act){
        float u = (lane==0) ? uv : -d;
        dummy_s[c] = (lane==0) ? 1.0f : 0.0f;
        mark[j] = u;
        atomicOr(&dead_s[c>>5], 1u << (c&31));
      }
      if (lane == 0) atomicOr(&sel_s[node>>5], 1u << (node&31));
      __syncthreads();
      u32 supp[8];
      #pragma unroll
      for (int w=0; w<8; ++w) supp[w] = rv[w];
      supp[r>>5] |= 1u << (r&31);
      #pragma unroll
      for (int q=0; q<4; ++q){
        int cc = lane*4 + q;
        double dy = 0.0;
        #pragma unroll
        for (int w=0; w<8; ++w){
          u32 m = bm_s[(size_t)(base+cc)*NWORDS + w] & supp[w]; int b0 = w<<5;
          while (m){ int jj=__ffs((int)m)-1; m&=m-1; dy += (double)mark[b0+jj]; }
        }
        if (dy != 0.0) y_s[base+cc] += dy;
      }
      __syncthreads();
      if (act) mark[j] = 0.0f;
      dwA = dead_s[nodeA>>5];  // re-read: this take may have killed nodeA
    } else {
      if (act) mark[j] = 0.0f;
    }
    __syncthreads();
  }

  for (int t = lane; t < NN; t += 64){
    float sv = ((sel_s[t>>5] >> (t&31)) & 1u) ? 1.0f : 0.0f;
    selw[t] = sv; out_sel[t] = sv;
  }
}

// ---------------- outputs ----------------
__global__ void k_xpool(const float* __restrict__ x, const float* __restrict__ selw, float* __restrict__ out){
  int t = blockIdx.x*256+threadIdx.x;
  if(t >= NN*(DD/4)) return;
  int i = t >> 7;
  float s = selw[i];
  float4 v = ((const float4*)x)[t];
  v.x*=s; v.y*=s; v.z*=s; v.w*=s;
  ((float4*)out)[t] = v;
}

__global__ void k_adj(const u32* __restrict__ bm, const u32* __restrict__ bm2,
                      const float* __restrict__ selw, float* __restrict__ outadj){
  int r = blockIdx.x;
  int c = blockIdx.y*256 + threadIdx.x;
  float val = 0.0f;
  if ((r>>8)==(c>>8) && r!=c && selw[r]!=0.0f && selw[c]!=0.0f){
    int lc = c & 255;
    u32 any = (bm2[r*NWORDS + (lc>>5)] >> (lc&31)) & 1u;
    if(!any){
      #pragma unroll
      for(int w=0;w<NWORDS;++w) any |= (bm2[r*NWORDS+w] & bm[c*NWORDS+w]);
    }
    val = any ? 1.0f : 0.0f;
  }
  outadj[(size_t)r*2048 + c] = val;
}

extern "C" void kernel_launch(void* const* d_in, const int* in_sizes, int n_in,
                              void* d_out, int out_size, void* d_ws, size_t ws_size,
                              hipStream_t stream){
  const float* x  = (const float*)d_in[0];
  const int* ei   = (const int*)d_in[1];
  const float* w11=(const float*)d_in[3];  const float* b11=(const float*)d_in[4];
  const float* w12=(const float*)d_in[5];  const float* b12=(const float*)d_in[6];
  const float* w13=(const float*)d_in[7];  const float* b13=(const float*)d_in[8];
  const float* w21=(const float*)d_in[9];  const float* b21=(const float*)d_in[10];
  const float* w22=(const float*)d_in[11]; const float* b22=(const float*)d_in[12];
  const float* w23=(const float*)d_in[13]; const float* b23=(const float*)d_in[14];
  const float* w31=(const float*)d_in[15]; const float* b31=(const float*)d_in[16];
  const float* w32=(const float*)d_in[17]; const float* b32=(const float*)d_in[18];
  const float* w33=(const float*)d_in[19]; const float* b33=(const float*)d_in[20];

  char* ws = (char*)d_ws;
  u32* bm    = (u32*)(ws + 0);
  u32* bm2   = (u32*)(ws + 65536);
  int* deg   = (int*)(ws + 131072);
  float* Vn  = (float*)(ws + 139264);
  float* ent = (float*)(ws + 147456);
  float* uarr= (float*)(ws + 155648);
  float* prob= (float*)(ws + 163840);
  int* order = (int*)(ws + 172032);
  float* selw= (float*)(ws + 180224);
  double* yg = (double*)(ws + 196608);
  double* cg = (double*)(ws + 212992);
  double* gam= (double*)(ws + 213056);
  u8* nbrl   = (u8*)(ws + 215040);   // 2048*48 = 98304
  u8* cntg   = (u8*)(ws + 313344);   // 2048
  u32* dead0 = (u32*)(ws + 315392);  // 256
  float* buf0= (float*)(ws + (1<<20));
  float* buf1= (float*)(ws + (1<<20) + (size_t)NN*DD*4);

  float* out = (float*)d_out;
  float* out_xp   = out;
  float* out_adj  = out + 1048576;
  float* out_sel  = out + 1048576 + 4194304;
  float* out_loss = out + 1048576 + 4194304 + 2048;

  hipFuncSetAttribute((const void*)k_scan, hipFuncAttributeMaxDynamicSharedMemorySize, 108544);

  k_zero_bm<<<65,256,0,stream>>>(bm, dead0);
  k_scatter<<<128,256,0,stream>>>(ei, bm);
  k_bm2_deg<<<8,256,0,stream>>>(bm, bm2, deg, nbrl, cntg, dead0);
  k_vn<<<512,256,0,stream>>>(x, bm, deg, Vn);
  k_softent<<<8,256,0,stream>>>(Vn, ent);
  k_u<<<8,256,0,stream>>>(bm, ent, uarr);
  k_h1<<<4096,256,0,stream>>>(uarr, w11, b11, buf0);
  dim3 gg(32,8);
  k_gemm<0><<<gg,256,0,stream>>>(buf0, w12, b12, buf1);
  k_gemm<1><<<gg,256,0,stream>>>(buf1, w13, b13, buf0);
  k_spmm_add<<<512,256,0,stream>>>(buf0, bm, buf1);
  k_gemm<0><<<gg,256,0,stream>>>(buf1, w21, b21, buf0);
  k_gemm<0><<<gg,256,0,stream>>>(buf0, w22, b22, buf1);
  k_gemm<1><<<gg,256,0,stream>>>(buf1, w23, b23, buf0);
  k_spmm_add<<<512,256,0,stream>>>(buf0, bm, buf1);
  k_gemm<0><<<gg,256,0,stream>>>(buf1, w31, b31, buf0);
  k_gemm<0><<<gg,256,0,stream>>>(buf0, w32, b32, buf1);
  k_gemv_prob<<<512,256,0,stream>>>(buf1, w33, b33, prob);
  k_y<<<8,256,0,stream>>>(bm, prob, ent, yg, cg, gam);
  k_sort<<<1,1024,0,stream>>>(prob, order);
  k_scan<<<1,64,108544,stream>>>(bm, nbrl, cntg, dead0, ent, prob, order, yg, cg, gam, selw, out_sel, out_loss);
  k_xpool<<<1024,256,0,stream>>>(x, selw, out_xp);
  dim3 ga(2048,8);
  k_adj<<<ga,256,0,stream>>>(bm, bm2, selw, out_adj);
}